// Round 6
// baseline (528.820 us; speedup 1.0000x reference)
//
#include <hip/hip_runtime.h>

#define N_NODES 100000
#define NPAD    100096      // multiple of 256 so gather/mm blocks need no row clamp
#define N_EDGES 1600000
#define FDIM 128
#define GDIM 64
#define CDIM 10

#define BSH   9
#define BSIZE 512           // nodes per bucket
#define NB    196           // ceil(N_NODES / BSIZE)
#define EPB   8192          // edges per chunk in prep's histogram -> 196 chunks
#define EPB_C 6250          // edges per bscatter block -> 256 blocks exactly

// Sliced feature layout: h[s][node][16], s = feature>>4. A slice is 3.2 MB
// contiguous -> fits one XCD's 4 MB L2. k_gather pins slice = bid&7 so each
// XCD's random neighbor reads become L2 HITS (the 2.2 TB/s "floor" measured
// in R0-R2 was the L2-miss random-line tier; this removes the misses).
#define NSLICE 8
#define SLICE_ELS ((size_t)NPAD * 16)

typedef unsigned short us16;
typedef us16 usx8 __attribute__((ext_vector_type(8)));
typedef short bfrag __attribute__((ext_vector_type(8)));   // 8 bf16 = 4 VGPRs
typedef float f32x4 __attribute__((ext_vector_type(4)));

__device__ __forceinline__ float bf2f(us16 u) {
  return __uint_as_float(((unsigned)u) << 16);
}
__device__ __forceinline__ us16 f2bf(float f) {
  unsigned u = __float_as_uint(f);
  u += 0x7FFFu + ((u >> 16) & 1u);   // RNE
  return (us16)(u >> 16);
}

// ---------------- prep: cast x (to sliced), pack W, zero pooled, histogram ----
// bcnt/bcursor zeroed by memsetAsync BEFORE this kernel.
// R4 lesson: no per-node global degree atomics (partial-line writeback ~120us).
#define CB 6256            // NPAD*16/256 cast blocks (8 els/thread)
__global__ __launch_bounds__(256) void k_prep(
    const float* __restrict__ x, us16* __restrict__ xb,
    const float* __restrict__ Wrel1, const float* __restrict__ Wroot1,
    const float* __restrict__ Wrel2, const float* __restrict__ Wroot2,
    const float* __restrict__ Wrel3, const float* __restrict__ Wroot3,
    us16* __restrict__ Wp, float* __restrict__ pooled,
    const int* __restrict__ edst, int* __restrict__ bcnt) {
  int bx = blockIdx.x, tid = threadIdx.x;
  if (bx < CB) {
    int j = bx * 256 + tid;          // 0 .. NPAD*16
    int s = j / (NPAD * 2);          // slice
    int r = j - s * (NPAD * 2);
    int n = r >> 1, h = r & 1;       // node, 8-el half of the 16-el slice row
    usx8 o;
#pragma unroll
    for (int k = 0; k < 8; ++k) o[k] = 0;
    if (n < N_NODES) {
      const float* xp = x + (size_t)n * FDIM + s * 16 + h * 8;
      float4 a = *(const float4*)xp;
      float4 b = *(const float4*)(xp + 4);
      o[0]=f2bf(a.x); o[1]=f2bf(a.y); o[2]=f2bf(a.z); o[3]=f2bf(a.w);
      o[4]=f2bf(b.x); o[5]=f2bf(b.y); o[6]=f2bf(b.z); o[7]=f2bf(b.w);
    }
    *(usx8*)(xb + (size_t)s * SLICE_ELS + (size_t)n * 16 + h * 8) = o;
  } else if (bx < CB + 384) {
    int wb = bx - CB;             // 0..383
    int l = wb >> 7;              // layer
    const float* Wrel  = (l == 0) ? Wrel1  : (l == 1) ? Wrel2  : Wrel3;
    const float* Wroot = (l == 0) ? Wroot1 : (l == 1) ? Wroot2 : Wroot3;
    int idx = (wb & 127) * 256 + tid;   // 0..32767
    int k = idx >> 7;       // 0..255
    int c = idx & 127;      // output col
    float v = (k < 128) ? Wrel[c * 128 + k] : Wroot[c * 128 + k - 128];
    Wp[(size_t)l * 32768 + (((k >> 3) * 128 + c) << 3) + (k & 7)] = f2bf(v);
  } else if (bx == CB + 384) {
    for (int i = tid; i < GDIM * FDIM; i += 256) pooled[i] = 0.f;
  } else {
    // bucket histogram over edge chunk
    __shared__ int h[NB];
    int cb = bx - (CB + 385);
    for (int i = tid; i < NB; i += 256) h[i] = 0;
    __syncthreads();
    int s0 = cb * EPB;
    int e0 = s0 + EPB; if (e0 > N_EDGES) e0 = N_EDGES;
    for (int i = s0 + tid; i < e0; i += 256) atomicAdd(&h[edst[i] >> BSH], 1);
    __syncthreads();
    for (int i = tid; i < NB; i += 256)
      if (h[i]) atomicAdd(&bcnt[i], h[i]);
  }
}

// In-block exclusive scan of bcnt[NB] -> boffL (LDS), wave-shuffle based.
__device__ __forceinline__ void scan_bcnt(const int* __restrict__ bcnt,
                                          int* wsum /*[>=4]*/,
                                          int* boffL /*[NB]*/, int tid) {
  int v = (tid < NB) ? bcnt[tid] : 0;
  int lane = tid & 63;
  int x = v;
#pragma unroll
  for (int d = 1; d < 64; d <<= 1) {
    int t = __shfl_up(x, d, 64);
    if (lane >= d) x += t;
  }
  if (tid < 256 && lane == 63) wsum[tid >> 6] = x;
  __syncthreads();
  if (tid == 0) {
    int r = 0;
#pragma unroll
    for (int i = 0; i < 4; ++i) { int t = wsum[i]; wsum[i] = r; r += t; }
  }
  __syncthreads();
  if (tid < NB) boffL[tid] = x - v + wsum[tid >> 6];   // exclusive
  __syncthreads();
}

// Pass C: counting-sort edges into bucket-contiguous runs.
__global__ __launch_bounds__(1024) void k_bscatter(
    const int* __restrict__ src, const int* __restrict__ dst,
    const int* __restrict__ bcnt, int* __restrict__ bcursor,
    int* __restrict__ ebuf) {
  __shared__ int wsum[4];
  __shared__ int boffL[NB];
  __shared__ int h[NB];
  __shared__ int base[NB];
  __shared__ int lc[NB];
  int tid = threadIdx.x;
  for (int i = tid; i < NB; i += 1024) h[i] = 0;
  scan_bcnt(bcnt, wsum, boffL, tid);
  int s0 = blockIdx.x * EPB_C;
  int e0 = s0 + EPB_C; if (e0 > N_EDGES) e0 = N_EDGES;
  for (int i = s0 + tid; i < e0; i += 1024) atomicAdd(&h[dst[i] >> BSH], 1);
  __syncthreads();
  for (int i = tid; i < NB; i += 1024) {
    base[i] = h[i] ? (boffL[i] + atomicAdd(&bcursor[i], h[i])) : 0;
    lc[i] = 0;
  }
  __syncthreads();
  for (int i = s0 + tid; i < e0; i += 1024) {
    int d = dst[i];
    int b = d >> BSH;
    int lp = atomicAdd(&lc[b], 1);
    ebuf[base[b] + lp] = (src[i] << BSH) | (d & (BSIZE - 1));
  }
}

// Pass D: per-bucket histogram -> row_ptr, LDS-cursor scatter.
__global__ __launch_bounds__(1024) void k_bucket_csr(
    const int* __restrict__ ebuf, const int* __restrict__ bcnt,
    int* __restrict__ row_ptr, int* __restrict__ csr_src) {
  __shared__ int wsum[8];
  __shared__ int boffL[NB];
  __shared__ int hist[BSIZE];
  __shared__ int cur[BSIZE];
  __shared__ int se[2];
  int b = blockIdx.x, tid = threadIdx.x;
  if (tid < BSIZE) hist[tid] = 0;
  scan_bcnt(bcnt, wsum, boffL, tid);
  if (tid == 0) {
    se[0] = boffL[b];
    se[1] = (b + 1 < NB) ? boffL[b + 1] : N_EDGES;
    if (b == 0) row_ptr[N_NODES] = N_EDGES;
  }
  __syncthreads();
  int eoff = se[0], ecnt = se[1] - se[0];
  int base = b * BSIZE;
  for (int i = tid; i < ecnt; i += 1024)
    atomicAdd(&hist[ebuf[eoff + i] & (BSIZE - 1)], 1);
  __syncthreads();
  int v = (tid < BSIZE) ? hist[tid] : 0;
  int lane = tid & 63;
  int x = v;
#pragma unroll
  for (int d = 1; d < 64; d <<= 1) {
    int t = __shfl_up(x, d, 64);
    if (lane >= d) x += t;
  }
  if (tid < BSIZE && lane == 63) wsum[tid >> 6] = x;
  __syncthreads();
  if (tid == 0) {
    int r = 0;
#pragma unroll
    for (int i = 0; i < 8; ++i) { int t = wsum[i]; wsum[i] = r; r += t; }
  }
  __syncthreads();
  if (tid < BSIZE) {
    int ex = x - v + wsum[tid >> 6];
    int node = base + tid;
    if (node < N_NODES) row_ptr[node] = eoff + ex;
    cur[tid] = ex;
  }
  __syncthreads();
  for (int i = tid; i < ecnt; i += 1024) {
    int e = ebuf[eoff + i];
    int lp = atomicAdd(&cur[e & (BSIZE - 1)], 1);
    csr_src[eoff + lp] = e >> BSH;
  }
}

// ---------------- phase A: per-XCD feature-slice gather -----------------------
// slice = bid & 7 rides the round-robin block->XCD dispatch: all blocks of a
// slice land on one XCD, whose gather footprint (3.2 MB contiguous) is then
// L2-resident. 2 lanes per node, 4-edge unroll (8 x 16B loads in flight).
__global__ __launch_bounds__(512) void k_gather(
    const us16* __restrict__ hin, const int* __restrict__ row_ptr,
    const int* __restrict__ csr_src, us16* __restrict__ agg) {
  int slice = blockIdx.x & 7, chunk = blockIdx.x >> 3;
  int tid = threadIdx.x;
  int slot = tid >> 1, half = tid & 1;
  int node = chunk * 256 + slot;
  const us16* tbl = hin + (size_t)slice * SLICE_ELS + half * 8;
  float a0=0.f,a1=0.f,a2=0.f,a3=0.f,a4=0.f,a5=0.f,a6=0.f,a7=0.f;
  if (node < N_NODES) {
    int s = row_ptr[node], e = row_ptr[node + 1];
    int p = s;
    for (; p + 4 <= e; p += 4) {
      int j0 = csr_src[p],     j1 = csr_src[p + 1];
      int j2 = csr_src[p + 2], j3 = csr_src[p + 3];
      usx8 v0 = *(const usx8*)(tbl + (size_t)j0 * 16);
      usx8 v1 = *(const usx8*)(tbl + (size_t)j1 * 16);
      usx8 v2 = *(const usx8*)(tbl + (size_t)j2 * 16);
      usx8 v3 = *(const usx8*)(tbl + (size_t)j3 * 16);
      a0 += bf2f(v0[0]) + bf2f(v1[0]) + bf2f(v2[0]) + bf2f(v3[0]);
      a1 += bf2f(v0[1]) + bf2f(v1[1]) + bf2f(v2[1]) + bf2f(v3[1]);
      a2 += bf2f(v0[2]) + bf2f(v1[2]) + bf2f(v2[2]) + bf2f(v3[2]);
      a3 += bf2f(v0[3]) + bf2f(v1[3]) + bf2f(v2[3]) + bf2f(v3[3]);
      a4 += bf2f(v0[4]) + bf2f(v1[4]) + bf2f(v2[4]) + bf2f(v3[4]);
      a5 += bf2f(v0[5]) + bf2f(v1[5]) + bf2f(v2[5]) + bf2f(v3[5]);
      a6 += bf2f(v0[6]) + bf2f(v1[6]) + bf2f(v2[6]) + bf2f(v3[6]);
      a7 += bf2f(v0[7]) + bf2f(v1[7]) + bf2f(v2[7]) + bf2f(v3[7]);
    }
    for (; p < e; ++p) {
      int j = csr_src[p];
      usx8 v = *(const usx8*)(tbl + (size_t)j * 16);
      a0 += bf2f(v[0]); a1 += bf2f(v[1]); a2 += bf2f(v[2]); a3 += bf2f(v[3]);
      a4 += bf2f(v[4]); a5 += bf2f(v[5]); a6 += bf2f(v[6]); a7 += bf2f(v[7]);
    }
  }
  usx8 o;
  o[0]=f2bf(a0); o[1]=f2bf(a1); o[2]=f2bf(a2); o[3]=f2bf(a3);
  o[4]=f2bf(a4); o[5]=f2bf(a5); o[6]=f2bf(a6); o[7]=f2bf(a7);
  *(usx8*)(agg + (size_t)slice * SLICE_ELS + (size_t)node * 16 + half * 8) = o;
}

// ---------------- phase B: MFMA dual GEMM + epilogue --------------------------
// out = relu(agg @ Wrel^T + hin @ Wroot^T + b). A-frags read straight from
// sliced global (agg for k<128, hin for k>=128): feature f0 = c*32+quad*8
// lives at slice 2*(c&3)+(quad>>1), offset (quad&1)*8. No LDS at all.
#define LROWS 128
__global__ __launch_bounds__(512) void k_mm(
    const us16* __restrict__ hin, const us16* __restrict__ agg,
    const us16* __restrict__ Wp, const float* __restrict__ bias,
    us16* __restrict__ out, const int* __restrict__ batch,
    float* __restrict__ pooled) {
  int tid = threadIdx.x;
  int node0 = blockIdx.x * LROWS;
  int wave = tid >> 6, lane = tid & 63;
  int m = lane & 15, quad = lane >> 4;
  size_t rowA = (size_t)(node0 + wave * 16 + m);
  int qh = quad >> 1, qo = (quad & 1) * 8;
  f32x4 acc[8];
#pragma unroll
  for (int t = 0; t < 8; ++t) acc[t] = (f32x4){0.f, 0.f, 0.f, 0.f};

#pragma unroll 1
  for (int c = 0; c < 8; ++c) {
    const us16* srcb = (c < 4) ? agg : hin;
    int s = 2 * (c & 3) + qh;
    bfrag a = *(const bfrag*)(srcb + (size_t)s * SLICE_ELS + rowA * 16 + qo);
    int kq = c * 4 + quad;
    const us16* wbase = Wp + (((size_t)kq * 128 + m) << 3);
#pragma unroll
    for (int t = 0; t < 8; ++t) {
      bfrag b = *(const bfrag*)(wbase + t * 128);   // 16 cols * 8 j
      acc[t] = __builtin_amdgcn_mfma_f32_16x16x32_bf16(a, b, acc[t], 0, 0, 0);
    }
  }
  // epilogue: D lane mapping col = lane&15 (within t-tile), row = quad*4 + i
  int w16 = node0 + wave * 16;
  int orow0 = w16 + quad * 4;
  if (pooled == nullptr) {
#pragma unroll
    for (int t = 0; t < 8; ++t) {
      int col = t * 16 + m;
      float bv = bias[col];
#pragma unroll
      for (int i = 0; i < 4; ++i) {
        int r = orow0 + i;
        if (r < N_NODES)   // sliced store: slice = t, within-slice col = m
          out[(size_t)t * SLICE_ELS + (size_t)r * 16 + m] =
              f2bf(fmaxf(acc[t][i] + bv, 0.f));
      }
    }
  } else {
    // fused mean-pool (sum phase): no global store of h3
    int rlast = w16 + 15;
    int gfirst = batch[(w16 < N_NODES) ? w16 : (N_NODES - 1)];
    int glast  = batch[(rlast < N_NODES) ? rlast : (N_NODES - 1)];
    bool uniform = (gfirst == glast) && (rlast < N_NODES);
    if (uniform) {
#pragma unroll
      for (int t = 0; t < 8; ++t) {
        int col = t * 16 + m;
        float bv = bias[col];
        float v = fmaxf(acc[t][0] + bv, 0.f) + fmaxf(acc[t][1] + bv, 0.f) +
                  fmaxf(acc[t][2] + bv, 0.f) + fmaxf(acc[t][3] + bv, 0.f);
        v += __shfl_xor(v, 16);
        v += __shfl_xor(v, 32);
        if (quad == 0) atomicAdd(&pooled[gfirst * FDIM + col], v);
      }
    } else {
      int g[4];
#pragma unroll
      for (int i = 0; i < 4; ++i) {
        int r = orow0 + i;
        g[i] = batch[(r < N_NODES) ? r : (N_NODES - 1)];
      }
#pragma unroll
      for (int t = 0; t < 8; ++t) {
        int col = t * 16 + m;
        float bv = bias[col];
#pragma unroll
        for (int i = 0; i < 4; ++i) {
          int r = orow0 + i;
          if (r < N_NODES)
            atomicAdd(&pooled[g[i] * FDIM + col], fmaxf(acc[t][i] + bv, 0.f));
        }
      }
    }
  }
}

// ---------------- MLP head + log_softmax (divides pooled sums by counts) ------
__global__ __launch_bounds__(128) void k_head(
    const float* __restrict__ pooled, const int* __restrict__ batch,
    const float* __restrict__ Wl1, const float* __restrict__ bl1,
    const float* __restrict__ Wl2, const float* __restrict__ bl2,
    float* __restrict__ out) {
  int g = blockIdx.x;
  __shared__ int sb[2];
  __shared__ float p[128];
  __shared__ float h1[64];
  __shared__ float logit[CDIM];
  if (threadIdx.x < 2) {
    int key = g + (int)threadIdx.x;
    int lo = 0, hi = N_NODES;
    while (lo < hi) {
      int mid = (lo + hi) >> 1;
      if (batch[mid] < key) lo = mid + 1; else hi = mid;
    }
    sb[threadIdx.x] = lo;
  }
  __syncthreads();
  float cnt = (float)(sb[1] - sb[0]);
  p[threadIdx.x] = pooled[g * FDIM + threadIdx.x] / fmaxf(cnt, 1.f);
  __syncthreads();
  if (threadIdx.x < 64) {
    float acc = bl1[threadIdx.x];
    for (int k = 0; k < 128; ++k) acc += p[k] * Wl1[threadIdx.x * 128 + k];
    h1[threadIdx.x] = fmaxf(acc, 0.f);
  }
  __syncthreads();
  if (threadIdx.x < CDIM) {
    float acc = bl2[threadIdx.x];
    for (int k = 0; k < 64; ++k) acc += h1[k] * Wl2[threadIdx.x * 64 + k];
    logit[threadIdx.x] = acc;
  }
  __syncthreads();
  if (threadIdx.x == 0) {
    float m = -1e30f;
    for (int c = 0; c < CDIM; ++c) m = fmaxf(m, logit[c]);
    float s = 0.f;
    for (int c = 0; c < CDIM; ++c) s += expf(logit[c] - m);
    float ls = logf(s);
    for (int c = 0; c < CDIM; ++c) out[g * CDIM + c] = logit[c] - m - ls;
  }
}

extern "C" void kernel_launch(void* const* d_in, const int* in_sizes, int n_in,
                              void* d_out, int out_size, void* d_ws, size_t ws_size,
                              hipStream_t stream) {
  const float* x      = (const float*)d_in[0];
  const int* edge_idx = (const int*)d_in[1];
  const int* batch    = (const int*)d_in[2];
  const float* W1_rel  = (const float*)d_in[4];
  const float* b1_rel  = (const float*)d_in[5];
  const float* W1_root = (const float*)d_in[6];
  const float* W2_rel  = (const float*)d_in[7];
  const float* b2_rel  = (const float*)d_in[8];
  const float* W2_root = (const float*)d_in[9];
  const float* W3_rel  = (const float*)d_in[10];
  const float* b3_rel  = (const float*)d_in[11];
  const float* W3_root = (const float*)d_in[12];
  const float* Wl1     = (const float*)d_in[13];
  const float* bl1     = (const float*)d_in[14];
  const float* Wl2     = (const float*)d_in[15];
  const float* bl2     = (const float*)d_in[16];
  const int* esrc = edge_idx;
  const int* edst = edge_idx + N_EDGES;

  char* ws = (char*)d_ws;
  size_t off = 0;
  auto alloc = [&](size_t bytes) {
    void* p = ws + off;
    off += (bytes + 255) & ~(size_t)255;
    return p;
  };
  int* row_ptr  = (int*)alloc((N_NODES + 1) * sizeof(int));
  int* bc2      = (int*)alloc(2 * NB * sizeof(int));   // [bcnt | bcursor]
  int* csr_src  = (int*)alloc(N_EDGES * sizeof(int));
  us16* xb      = (us16*)alloc((size_t)NPAD * FDIM * sizeof(us16));  // h0 / h2
  us16* hA      = (us16*)alloc((size_t)NPAD * FDIM * sizeof(us16));  // h1
  us16* agg     = (us16*)alloc((size_t)NPAD * FDIM * sizeof(us16));  // per-layer agg
  us16* Wp      = (us16*)alloc(3 * 32768 * sizeof(us16));
  float* pooled = (float*)alloc(GDIM * FDIM * sizeof(float));
  int* bcnt    = bc2;
  int* bcursor = bc2 + NB;
  // ebuf (6.4 MB, packed) aliases hA (25.6 MB): dead before B1 writes hA
  int* ebuf     = (int*)hA;

  hipMemsetAsync(bc2, 0, 2 * NB * sizeof(int), stream);

  // prep: cast x to sliced bf16, pack W, zero pooled, bucket-histogram edges
  k_prep<<<CB + 384 + 1 + NB, 256, 0, stream>>>(
      x, xb, W1_rel, W1_root, W2_rel, W2_root, W3_rel, W3_root, Wp, pooled,
      edst, bcnt);

  k_bscatter<<<(N_EDGES + EPB_C - 1) / EPB_C, 1024, 0, stream>>>(
      esrc, edst, bcnt, bcursor, ebuf);
  k_bucket_csr<<<NB, 1024, 0, stream>>>(ebuf, bcnt, row_ptr, csr_src);

  int ggrid = (NPAD / 256) * NSLICE;       // 391*8 = 3128
  int mgrid = NPAD / LROWS;                // 782

  // layer 1: h0=xb -> h1=hA
  k_gather<<<ggrid, 512, 0, stream>>>(xb, row_ptr, csr_src, agg);
  k_mm<<<mgrid, 512, 0, stream>>>(xb, agg, Wp, b1_rel, hA, batch, nullptr);
  // layer 2: h1=hA -> h2=xb (x-cast copy dead after B1)
  k_gather<<<ggrid, 512, 0, stream>>>(hA, row_ptr, csr_src, agg);
  k_mm<<<mgrid, 512, 0, stream>>>(hA, agg, Wp + 32768, b2_rel, xb, batch, nullptr);
  // layer 3: h2=xb -> pooled sums (no h3 store; out arg unused)
  k_gather<<<ggrid, 512, 0, stream>>>(xb, row_ptr, csr_src, agg);
  k_mm<<<mgrid, 512, 0, stream>>>(xb, agg, Wp + 65536, b3_rel, hA, batch, pooled);

  k_head<<<GDIM, 128, 0, stream>>>(pooled, batch, Wl1, bl1, Wl2, bl2, (float*)d_out);
}

// Round 7
// 375.845 us; speedup vs baseline: 1.4070x; 1.4070x over previous
//
#include <hip/hip_runtime.h>

#define N_NODES 100000
#define NPAD    100096      // multiple of 128 so layer blocks need no row clamp
#define N_EDGES 1600000
#define FDIM 128
#define GDIM 64
#define CDIM 10

#define BSH   9
#define BSIZE 512           // nodes per bucket
#define NB    196           // ceil(N_NODES / BSIZE)
#define EPB   8192          // edges per chunk in prep's histogram -> 196 chunks
#define EPB_C 6250          // edges per bscatter block -> 256 blocks exactly

typedef unsigned short us16;
typedef unsigned char u8;
typedef us16 usx8 __attribute__((ext_vector_type(8)));
typedef short bfrag __attribute__((ext_vector_type(8)));   // 8 bf16 = 4 VGPRs
typedef float f32x4 __attribute__((ext_vector_type(4)));
typedef float f32x2 __attribute__((ext_vector_type(2)));

__device__ __forceinline__ float bf2f(us16 u) {
  return __uint_as_float(((unsigned)u) << 16);
}
__device__ __forceinline__ us16 f2bf(float f) {
  unsigned u = __float_as_uint(f);
  u += 0x7FFFu + ((u >> 16) & 1u);   // RNE
  return (us16)(u >> 16);
}

// accumulate 8 fp8 (e4m3, one uint2) into a[0..8)
__device__ __forceinline__ void acc_fp8x8(uint2 v, float* a) {
  f32x2 p0 = __builtin_amdgcn_cvt_pk_f32_fp8(v.x, false);
  f32x2 p1 = __builtin_amdgcn_cvt_pk_f32_fp8(v.x, true);
  f32x2 p2 = __builtin_amdgcn_cvt_pk_f32_fp8(v.y, false);
  f32x2 p3 = __builtin_amdgcn_cvt_pk_f32_fp8(v.y, true);
  a[0] += p0[0]; a[1] += p0[1]; a[2] += p1[0]; a[3] += p1[1];
  a[4] += p2[0]; a[5] += p2[1]; a[6] += p3[0]; a[7] += p3[1];
}

// ---------------- prep: cast x (bf16 + fp8), pack W, zero pooled, histogram ---
// bcnt/bcursor zeroed by memsetAsync BEFORE this kernel.
// R4 lesson: no per-node global degree atomics (partial-line writeback ~120us).
#define XB 6250            // N_NODES*FDIM/8/256 cast blocks
__global__ __launch_bounds__(256) void k_prep(
    const float* __restrict__ x, us16* __restrict__ xb, u8* __restrict__ xq,
    const float* __restrict__ Wrel1, const float* __restrict__ Wroot1,
    const float* __restrict__ Wrel2, const float* __restrict__ Wroot2,
    const float* __restrict__ Wrel3, const float* __restrict__ Wroot3,
    us16* __restrict__ Wp, float* __restrict__ pooled,
    const int* __restrict__ edst, int* __restrict__ bcnt) {
  int bx = blockIdx.x, tid = threadIdx.x;
  if (bx < XB) {
    size_t i = ((size_t)bx * 256 + tid) * 8;    // 8 floats per thread
    float4 a = *(const float4*)(x + i);
    float4 b = *(const float4*)(x + i + 4);
    usx8 o;
    o[0]=f2bf(a.x); o[1]=f2bf(a.y); o[2]=f2bf(a.z); o[3]=f2bf(a.w);
    o[4]=f2bf(b.x); o[5]=f2bf(b.y); o[6]=f2bf(b.z); o[7]=f2bf(b.w);
    *(usx8*)(xb + i) = o;
    int lo = __builtin_amdgcn_cvt_pk_fp8_f32(a.x, a.y, 0, false);
    lo     = __builtin_amdgcn_cvt_pk_fp8_f32(a.z, a.w, lo, true);
    int hi = __builtin_amdgcn_cvt_pk_fp8_f32(b.x, b.y, 0, false);
    hi     = __builtin_amdgcn_cvt_pk_fp8_f32(b.z, b.w, hi, true);
    uint2 q; q.x = (unsigned)lo; q.y = (unsigned)hi;
    *(uint2*)(xq + i) = q;                       // 8 B contiguous per thread
  } else if (bx < XB + 384) {
    int wb = bx - XB;             // 0..383
    int l = wb >> 7;              // layer
    const float* Wrel  = (l == 0) ? Wrel1  : (l == 1) ? Wrel2  : Wrel3;
    const float* Wroot = (l == 0) ? Wroot1 : (l == 1) ? Wroot2 : Wroot3;
    int idx = (wb & 127) * 256 + tid;   // 0..32767
    int k = idx >> 7;       // 0..255
    int c = idx & 127;      // output col
    float v = (k < 128) ? Wrel[c * 128 + k] : Wroot[c * 128 + k - 128];
    Wp[(size_t)l * 32768 + (((k >> 3) * 128 + c) << 3) + (k & 7)] = f2bf(v);
  } else if (bx == XB + 384) {
    for (int i = tid; i < GDIM * FDIM; i += 256) pooled[i] = 0.f;
  } else {
    // bucket histogram over edge chunk
    __shared__ int h[NB];
    int cb = bx - (XB + 385);
    for (int i = tid; i < NB; i += 256) h[i] = 0;
    __syncthreads();
    int s0 = cb * EPB;
    int e0 = s0 + EPB; if (e0 > N_EDGES) e0 = N_EDGES;
    for (int i = s0 + tid; i < e0; i += 256) atomicAdd(&h[edst[i] >> BSH], 1);
    __syncthreads();
    for (int i = tid; i < NB; i += 256)
      if (h[i]) atomicAdd(&bcnt[i], h[i]);
  }
}

// In-block exclusive scan of bcnt[NB] -> boffL (LDS), wave-shuffle based.
__device__ __forceinline__ void scan_bcnt(const int* __restrict__ bcnt,
                                          int* wsum /*[>=4]*/,
                                          int* boffL /*[NB]*/, int tid) {
  int v = (tid < NB) ? bcnt[tid] : 0;
  int lane = tid & 63;
  int x = v;
#pragma unroll
  for (int d = 1; d < 64; d <<= 1) {
    int t = __shfl_up(x, d, 64);
    if (lane >= d) x += t;
  }
  if (tid < 256 && lane == 63) wsum[tid >> 6] = x;
  __syncthreads();
  if (tid == 0) {
    int r = 0;
#pragma unroll
    for (int i = 0; i < 4; ++i) { int t = wsum[i]; wsum[i] = r; r += t; }
  }
  __syncthreads();
  if (tid < NB) boffL[tid] = x - v + wsum[tid >> 6];   // exclusive
  __syncthreads();
}

// Pass C: counting-sort edges into bucket-contiguous runs.
// Record packed as (src << 9) | dst_local  (src < 2^17 -> fits 26 bits).
__global__ __launch_bounds__(1024) void k_bscatter(
    const int* __restrict__ src, const int* __restrict__ dst,
    const int* __restrict__ bcnt, int* __restrict__ bcursor,
    int* __restrict__ ebuf) {
  __shared__ int wsum[4];
  __shared__ int boffL[NB];
  __shared__ int h[NB];
  __shared__ int base[NB];
  __shared__ int lc[NB];
  int tid = threadIdx.x;
  for (int i = tid; i < NB; i += 1024) h[i] = 0;
  scan_bcnt(bcnt, wsum, boffL, tid);
  int s0 = blockIdx.x * EPB_C;
  int e0 = s0 + EPB_C; if (e0 > N_EDGES) e0 = N_EDGES;
  for (int i = s0 + tid; i < e0; i += 1024) atomicAdd(&h[dst[i] >> BSH], 1);
  __syncthreads();
  for (int i = tid; i < NB; i += 1024) {
    base[i] = h[i] ? (boffL[i] + atomicAdd(&bcursor[i], h[i])) : 0;
    lc[i] = 0;
  }
  __syncthreads();
  for (int i = s0 + tid; i < e0; i += 1024) {
    int d = dst[i];
    int b = d >> BSH;
    int lp = atomicAdd(&lc[b], 1);
    ebuf[base[b] + lp] = (src[i] << BSH) | (d & (BSIZE - 1));
  }
}

// Pass D: per-bucket histogram -> row_ptr, LDS-cursor scatter.
__global__ __launch_bounds__(1024) void k_bucket_csr(
    const int* __restrict__ ebuf, const int* __restrict__ bcnt,
    int* __restrict__ row_ptr, int* __restrict__ csr_src) {
  __shared__ int wsum[8];
  __shared__ int boffL[NB];
  __shared__ int hist[BSIZE];
  __shared__ int cur[BSIZE];
  __shared__ int se[2];
  int b = blockIdx.x, tid = threadIdx.x;
  if (tid < BSIZE) hist[tid] = 0;
  scan_bcnt(bcnt, wsum, boffL, tid);
  if (tid == 0) {
    se[0] = boffL[b];
    se[1] = (b + 1 < NB) ? boffL[b + 1] : N_EDGES;
    if (b == 0) row_ptr[N_NODES] = N_EDGES;
  }
  __syncthreads();
  int eoff = se[0], ecnt = se[1] - se[0];
  int base = b * BSIZE;
  for (int i = tid; i < ecnt; i += 1024)
    atomicAdd(&hist[ebuf[eoff + i] & (BSIZE - 1)], 1);
  __syncthreads();
  int v = (tid < BSIZE) ? hist[tid] : 0;
  int lane = tid & 63;
  int x = v;
#pragma unroll
  for (int d = 1; d < 64; d <<= 1) {
    int t = __shfl_up(x, d, 64);
    if (lane >= d) x += t;
  }
  if (tid < BSIZE && lane == 63) wsum[tid >> 6] = x;
  __syncthreads();
  if (tid == 0) {
    int r = 0;
#pragma unroll
    for (int i = 0; i < 8; ++i) { int t = wsum[i]; wsum[i] = r; r += t; }
  }
  __syncthreads();
  if (tid < BSIZE) {
    int ex = x - v + wsum[tid >> 6];
    int node = base + tid;
    if (node < N_NODES) row_ptr[node] = eoff + ex;
    cur[tid] = ex;
  }
  __syncthreads();
  for (int i = tid; i < ecnt; i += 1024) {
    int e = ebuf[eoff + i];
    int lp = atomicAdd(&cur[e & (BSIZE - 1)], 1);
    csr_src[eoff + lp] = e >> BSH;
  }
}

// ---------------- fused layer: fp8 gather-aggregate -> MFMA dual GEMM ---------
// out = relu(agg(hq_in) @ Wrel^T + hin @ Wroot^T + b).
// R1/R2/R6 established: gather is bound by compulsory HBM traffic (8 XCDs x
// table x 0.865 + csr) at ~2.2 TB/s random-access BW. fp8 table halves the
// compulsory bytes; root GEMM path / accumulation / MFMA all stay bf16/f32.
#define ASTR 136
#define LROWS 128
__global__ __launch_bounds__(512) void k_layer(
    const us16* __restrict__ hin, const u8* __restrict__ hq_in,
    const us16* __restrict__ Wp, const float* __restrict__ bias,
    const int* __restrict__ row_ptr, const int* __restrict__ csr_src,
    us16* __restrict__ out, u8* __restrict__ hq_out,
    const int* __restrict__ batch, float* __restrict__ pooled) {
  __shared__ us16 As[LROWS * ASTR];   // 34.8 KB
  int tid = threadIdx.x;
  int node0 = blockIdx.x * LROWS;
  int slot = tid >> 4;      // 0..31: node slot within round
  int lane16 = tid & 15;    // feature octet
  const u8* gbase = hq_in + lane16 * 8;   // 8 fp8 features per lane

  // ---- phase 1: aggregate 128 nodes (4 rounds x 32 concurrent), fp8 rows ----
#pragma unroll 1
  for (int rnd = 0; rnd < 4; ++rnd) {
    int node = node0 + rnd * 32 + slot;
    float a[8];
#pragma unroll
    for (int j = 0; j < 8; ++j) a[j] = 0.f;
    if (node < N_NODES) {
      int s = row_ptr[node], e = row_ptr[node + 1];
      int p = s;
      for (; p + 4 <= e; p += 4) {
        int j0 = csr_src[p], j1 = csr_src[p + 1];
        int j2 = csr_src[p + 2], j3 = csr_src[p + 3];
        uint2 v0 = *(const uint2*)(gbase + (size_t)j0 * FDIM);
        uint2 v1 = *(const uint2*)(gbase + (size_t)j1 * FDIM);
        uint2 v2 = *(const uint2*)(gbase + (size_t)j2 * FDIM);
        uint2 v3 = *(const uint2*)(gbase + (size_t)j3 * FDIM);
        acc_fp8x8(v0, a); acc_fp8x8(v1, a);
        acc_fp8x8(v2, a); acc_fp8x8(v3, a);
      }
      for (; p < e; ++p) {
        int j = csr_src[p];
        uint2 v = *(const uint2*)(gbase + (size_t)j * FDIM);
        acc_fp8x8(v, a);
      }
    }
    usx8 o;
#pragma unroll
    for (int j = 0; j < 8; ++j) o[j] = f2bf(a[j]);
    *(usx8*)&As[(rnd * 32 + slot) * ASTR + lane16 * 8] = o;
  }
  __syncthreads();

  // ---- phase 2: MFMA.  A agg-half from LDS, root-half from global (bf16),
  //      W b-frags straight from L1/L2.
  int wave = tid >> 6, lane = tid & 63;
  int m = lane & 15, quad = lane >> 4;
  size_t rowA = (size_t)(node0 + wave * 16 + m);
  const us16* baseH = hin + rowA * FDIM + quad * 8;
  const us16* aldsb = &As[(wave * 16 + m) * ASTR + quad * 8];
  f32x4 acc[8];
#pragma unroll
  for (int t = 0; t < 8; ++t) acc[t] = (f32x4){0.f, 0.f, 0.f, 0.f};

#pragma unroll 1
  for (int c = 0; c < 8; ++c) {
    bfrag a;
    if (c < 4) a = *(const bfrag*)(aldsb + c * 32);
    else       a = *(const bfrag*)(baseH + (c - 4) * 32);
    int kq = c * 4 + quad;
    const us16* wbase = Wp + (((size_t)kq * 128 + m) << 3);
#pragma unroll
    for (int t = 0; t < 8; ++t) {
      bfrag b = *(const bfrag*)(wbase + t * 128);   // 16 cols * 8 j
      acc[t] = __builtin_amdgcn_mfma_f32_16x16x32_bf16(a, b, acc[t], 0, 0, 0);
    }
  }
  // epilogue: D lane mapping col = lane&15 (within t-tile), row = quad*4 + i
  int w16 = node0 + wave * 16;
  int orow0 = w16 + quad * 4;
  if (pooled == nullptr) {
#pragma unroll
    for (int t = 0; t < 8; ++t) {
      int col = t * 16 + m;
      float bv = bias[col];
#pragma unroll
      for (int i = 0; i < 4; ++i) {
        int r = orow0 + i;
        if (r < N_NODES) {
          float val = fmaxf(acc[t][i] + bv, 0.f);
          out[(size_t)r * FDIM + col] = f2bf(val);
          // fp8 copy for next layer's gather. A wave covers all 128 B of each
          // of its rows in close succession -> L2 merges to full lines.
          hq_out[(size_t)r * FDIM + col] =
              (u8)(__builtin_amdgcn_cvt_pk_fp8_f32(val, val, 0, false) & 0xFF);
        }
      }
    }
  } else {
    // fused mean-pool (sum phase): no global store of h3
    int rlast = w16 + 15;
    int gfirst = batch[(w16 < N_NODES) ? w16 : (N_NODES - 1)];
    int glast  = batch[(rlast < N_NODES) ? rlast : (N_NODES - 1)];
    bool uniform = (gfirst == glast) && (rlast < N_NODES);
    if (uniform) {
#pragma unroll
      for (int t = 0; t < 8; ++t) {
        int col = t * 16 + m;
        float bv = bias[col];
        float v = fmaxf(acc[t][0] + bv, 0.f) + fmaxf(acc[t][1] + bv, 0.f) +
                  fmaxf(acc[t][2] + bv, 0.f) + fmaxf(acc[t][3] + bv, 0.f);
        v += __shfl_xor(v, 16);
        v += __shfl_xor(v, 32);
        if (quad == 0) atomicAdd(&pooled[gfirst * FDIM + col], v);
      }
    } else {
      int g[4];
#pragma unroll
      for (int i = 0; i < 4; ++i) {
        int r = orow0 + i;
        g[i] = batch[(r < N_NODES) ? r : (N_NODES - 1)];
      }
#pragma unroll
      for (int t = 0; t < 8; ++t) {
        int col = t * 16 + m;
        float bv = bias[col];
#pragma unroll
        for (int i = 0; i < 4; ++i) {
          int r = orow0 + i;
          if (r < N_NODES)
            atomicAdd(&pooled[g[i] * FDIM + col], fmaxf(acc[t][i] + bv, 0.f));
        }
      }
    }
  }
}

// ---------------- MLP head + log_softmax (divides pooled sums by counts) ------
__global__ __launch_bounds__(128) void k_head(
    const float* __restrict__ pooled, const int* __restrict__ batch,
    const float* __restrict__ Wl1, const float* __restrict__ bl1,
    const float* __restrict__ Wl2, const float* __restrict__ bl2,
    float* __restrict__ out) {
  int g = blockIdx.x;
  __shared__ int sb[2];
  __shared__ float p[128];
  __shared__ float h1[64];
  __shared__ float logit[CDIM];
  if (threadIdx.x < 2) {
    int key = g + (int)threadIdx.x;
    int lo = 0, hi = N_NODES;
    while (lo < hi) {
      int mid = (lo + hi) >> 1;
      if (batch[mid] < key) lo = mid + 1; else hi = mid;
    }
    sb[threadIdx.x] = lo;
  }
  __syncthreads();
  float cnt = (float)(sb[1] - sb[0]);
  p[threadIdx.x] = pooled[g * FDIM + threadIdx.x] / fmaxf(cnt, 1.f);
  __syncthreads();
  if (threadIdx.x < 64) {
    float acc = bl1[threadIdx.x];
    for (int k = 0; k < 128; ++k) acc += p[k] * Wl1[threadIdx.x * 128 + k];
    h1[threadIdx.x] = fmaxf(acc, 0.f);
  }
  __syncthreads();
  if (threadIdx.x < CDIM) {
    float acc = bl2[threadIdx.x];
    for (int k = 0; k < 64; ++k) acc += h1[k] * Wl2[threadIdx.x * 64 + k];
    logit[threadIdx.x] = acc;
  }
  __syncthreads();
  if (threadIdx.x == 0) {
    float m = -1e30f;
    for (int c = 0; c < CDIM; ++c) m = fmaxf(m, logit[c]);
    float s = 0.f;
    for (int c = 0; c < CDIM; ++c) s += expf(logit[c] - m);
    float ls = logf(s);
    for (int c = 0; c < CDIM; ++c) out[g * CDIM + c] = logit[c] - m - ls;
  }
}

extern "C" void kernel_launch(void* const* d_in, const int* in_sizes, int n_in,
                              void* d_out, int out_size, void* d_ws, size_t ws_size,
                              hipStream_t stream) {
  const float* x      = (const float*)d_in[0];
  const int* edge_idx = (const int*)d_in[1];
  const int* batch    = (const int*)d_in[2];
  const float* W1_rel  = (const float*)d_in[4];
  const float* b1_rel  = (const float*)d_in[5];
  const float* W1_root = (const float*)d_in[6];
  const float* W2_rel  = (const float*)d_in[7];
  const float* b2_rel  = (const float*)d_in[8];
  const float* W2_root = (const float*)d_in[9];
  const float* W3_rel  = (const float*)d_in[10];
  const float* b3_rel  = (const float*)d_in[11];
  const float* W3_root = (const float*)d_in[12];
  const float* Wl1     = (const float*)d_in[13];
  const float* bl1     = (const float*)d_in[14];
  const float* Wl2     = (const float*)d_in[15];
  const float* bl2     = (const float*)d_in[16];
  const int* esrc = edge_idx;
  const int* edst = edge_idx + N_EDGES;

  char* ws = (char*)d_ws;
  size_t off = 0;
  auto alloc = [&](size_t bytes) {
    void* p = ws + off;
    off += (bytes + 255) & ~(size_t)255;
    return p;
  };
  int* row_ptr  = (int*)alloc((N_NODES + 1) * sizeof(int));
  int* bc2      = (int*)alloc(2 * NB * sizeof(int));   // [bcnt | bcursor]
  int* csr_src  = (int*)alloc(N_EDGES * sizeof(int));
  us16* xb      = (us16*)alloc((size_t)NPAD * FDIM * sizeof(us16)); // h0, then h2
  us16* hA      = (us16*)alloc((size_t)NPAD * FDIM * sizeof(us16)); // h1
  u8*   xq      = (u8*)alloc((size_t)NPAD * FDIM);                  // q0, then q2
  u8*   hqA     = (u8*)alloc((size_t)NPAD * FDIM);                  // q1
  us16* Wp      = (us16*)alloc(3 * 32768 * sizeof(us16));
  float* pooled = (float*)alloc(GDIM * FDIM * sizeof(float));
  int* bcnt    = bc2;
  int* bcursor = bc2 + NB;
  // ebuf (6.4 MB, packed) aliases hA (25.6 MB): dead before layer-1 writes hA
  int* ebuf     = (int*)hA;

  hipMemsetAsync(bc2, 0, 2 * NB * sizeof(int), stream);

  // prep: cast x (bf16+fp8), pack W, zero pooled, bucket-histogram edges
  k_prep<<<XB + 384 + 1 + NB, 256, 0, stream>>>(
      x, xb, xq, W1_rel, W1_root, W2_rel, W2_root, W3_rel, W3_root, Wp, pooled,
      edst, bcnt);

  k_bscatter<<<(N_EDGES + EPB_C - 1) / EPB_C, 1024, 0, stream>>>(
      esrc, edst, bcnt, bcursor, ebuf);
  k_bucket_csr<<<NB, 1024, 0, stream>>>(ebuf, bcnt, row_ptr, csr_src);

  int lgrid = NPAD / LROWS;                // 782
  // layer 1: gather q0, root xb -> h1 (hA bf16 + hqA fp8)
  k_layer<<<lgrid, 512, 0, stream>>>(xb, xq, Wp, b1_rel, row_ptr, csr_src,
                                     hA, hqA, batch, nullptr);
  // layer 2: gather q1, root hA -> h2 (xb bf16 + xq fp8; both dead inputs reused)
  k_layer<<<lgrid, 512, 0, stream>>>(hA, hqA, Wp + 32768, b2_rel, row_ptr,
                                     csr_src, xb, xq, batch, nullptr);
  // layer 3: gather q2, root xb -> pooled sums (no h3 store)
  k_layer<<<lgrid, 512, 0, stream>>>(xb, xq, Wp + 65536, b3_rel, row_ptr,
                                     csr_src, hA, nullptr, batch, pooled);

  k_head<<<GDIM, 128, 0, stream>>>(pooled, batch, Wl1, bl1, Wl2, bl2, (float*)d_out);
}